// Round 5
// baseline (218.513 us; speedup 1.0000x reference)
//
#include <hip/hip_runtime.h>
#include <math.h>

#define IMG_W 2048
#define IMG_H 2048
#define BATCH 8
#define MAX_PEAKS ((BATCH * IMG_H * IMG_W) / 8)   // 4194304
#define NWORDS (BATCH * IMG_H * IMG_W / 32)       // 1048576
#define NFILL 2048                                // tail-fill blocks

#define TROWS 32            // output rows per block
#define SROWS (TROWS + 4)   // staged rows (incl. +-2 halo)
#define LROW 66             // float4 per LDS row: 4-float pad | 256 | 4-float pad

// ---------------------------------------------------------------------------
// K1: LDS-DMA staged separable 5x5 NMS.
// All four register-resident variants (dist-0/1/3, shuffle and shuffle-free)
// plateaued at ~2.3 TB/s: VGPR-destination loads cap the per-CU in-flight
// depth. This version stages via __builtin_amdgcn_global_load_lds (no VGPR
// destination, 9 DMAs issued back-to-back per wave, drained ONCE per tile by
// __syncthreads), then computes from LDS with stride-1 conflict-free
// ds_read_b128. Block = 32 rows x 256 cols, 38 KB LDS -> 4 blocks/CU.
// Compute pipeline (H-ring / m-ring / nibble transpose) is r4's, verified.
// mask bit = (s > 0) && (s >= 5x5 window max).
// ---------------------------------------------------------------------------

__device__ __forceinline__ void gl_lds16(const float* g, float* l) {
    __builtin_amdgcn_global_load_lds(
        (const __attribute__((address_space(1))) unsigned int*)g,
        (__attribute__((address_space(3))) unsigned int*)l, 16, 0, 0);
}

// horizontal 5-max of staged row (lb+u) -> HS; raw mid saved to MS
#define COMPL(u, HS, MS)                                                      \
  {                                                                           \
    const float4 qld = tile[(lb + (u)) * LROW + lane];                        \
    const float4 qm  = tile[(lb + (u)) * LROW + lane + 1];                    \
    const float4 qrd = tile[(lb + (u)) * LROW + lane + 2];                    \
    const float qlz = fixL ? NEG : qld.z;                                     \
    const float qlw = fixL ? NEG : qld.w;                                     \
    const float qrx = fixR ? NEG : qrd.x;                                     \
    const float qry = fixR ? NEG : qrd.y;                                     \
    const float ab = fmaxf(qm.x, qm.y);                                       \
    const float cd = fmaxf(qm.z, qm.w);                                       \
    const float bc = fmaxf(qm.y, qm.z);                                       \
    const float abcd = fmaxf(ab, cd);                                         \
    HS.x = fmaxf(fmaxf(qlz, qlw), fmaxf(ab, qm.z));                           \
    HS.y = fmaxf(qlw, abcd);                                                  \
    HS.z = fmaxf(abcd, qrx);                                                  \
    HS.w = fmaxf(fmaxf(bc, qm.w), fmaxf(qrx, qry));                           \
    MS = qm;                                                                  \
  }

#define OUT(MS, pos)                                                          \
  {                                                                           \
    const float vx = fmaxf(fmaxf(fmaxf(H0.x, H1.x), fmaxf(H2.x, H3.x)), H4.x);\
    const float vy = fmaxf(fmaxf(fmaxf(H0.y, H1.y), fmaxf(H2.y, H3.y)), H4.y);\
    const float vz = fmaxf(fmaxf(fmaxf(H0.z, H1.z), fmaxf(H2.z, H3.z)), H4.z);\
    const float vw = fmaxf(fmaxf(fmaxf(H0.w, H1.w), fmaxf(H2.w, H3.w)), H4.w);\
    unsigned nib = 0;                                                         \
    nib |= (MS.x > 0.0f && MS.x >= vx) ? 1u : 0u;                             \
    nib |= (MS.y > 0.0f && MS.y >= vy) ? 2u : 0u;                             \
    nib |= (MS.z > 0.0f && MS.z >= vz) ? 4u : 0u;                             \
    nib |= (MS.w > 0.0f && MS.w >= vw) ? 8u : 0u;                             \
    bacc |= nib << (4 * (pos));                                               \
  }

// 8x8 nibble transpose across each aligned lane-octet, then one coalesced
// 64-lane store: lane (o*8+l) holds the word of row (base+l), word-col
// (strip*8+o). Verified in r4.
#define MERGE()                                                               \
  {                                                                           \
    unsigned x = bacc, y;                                                     \
    y = __shfl_xor(x, 4);                                                     \
    x = (lane & 4) ? ((y >> 16) | (x & 0xFFFF0000u))                          \
                   : ((x & 0x0000FFFFu) | (y << 16));                         \
    y = __shfl_xor(x, 2);                                                     \
    x = (lane & 2) ? (((y >> 8) & 0x00FF00FFu) | (x & 0xFF00FF00u))           \
                   : ((x & 0x00FF00FFu) | ((y << 8) & 0xFF00FF00u));          \
    y = __shfl_xor(x, 1);                                                     \
    x = (lane & 1) ? (((y >> 4) & 0x0F0F0F0Fu) | (x & 0xF0F0F0F0u))           \
                   : ((x & 0x0F0F0F0Fu) | ((y << 4) & 0xF0F0F0F0u));          \
    words[wIdx0] = x;                                                         \
    cnt += __popc(x);                                                         \
  }

__global__ __launch_bounds__(256, 4) void nms_mask(const float* __restrict__ scores,
                                                   unsigned* __restrict__ words,
                                                   unsigned* __restrict__ bsum2) {
    __shared__ float4 tile[SROWS * LROW];   // 38016 B
    __shared__ unsigned wcnt[4];
    const int t = threadIdx.x;
    const int lane = t & 63;
    const int wv = t >> 6;
    // XCD swizzle: one image per XCD; consecutive blocks = consecutive row
    // chunks so the 4-row vertical halo L2-hits.
    const int b = blockIdx.x;                  // 0..4095
    const int L = (b >> 3) + (b & 7) * 512;
    const int img = L >> 9;
    const int rem = L & 511;
    const int strip = rem >> 6;                // 8 strips of 256 cols
    const int chunk = rem & 63;                // 64 chunks of 32 rows
    const int r0 = chunk * TROWS;
    const int c0 = strip * 256;
    const size_t imgBase = (size_t)img * ((size_t)IMG_H * IMG_W);
    const float* ibase = scores + imgBase;
    const float NEG = -INFINITY;

    // ---- stage main rows: wave wv DMAs rows wv*9 .. wv*9+8 (1 KB each) ----
    {
        const float* gl = ibase + c0 + lane * 4;
#pragma unroll
        for (int k = 0; k < 9; ++k) {
            const int rr = wv * 9 + k;
            int gr = r0 - 2 + rr;
            gr = gr < 0 ? 0 : (gr > IMG_H - 1 ? IMG_H - 1 : gr);
            gl_lds16(gl + (size_t)gr * IMG_W, (float*)&tile[rr * LROW + 1]);
        }
    }
    // ---- side pads via regular load + ds_write: wave0 left, wave1 right ----
    if (wv < 2 && lane < SROWS) {
        const int rr = lane;
        int gr = r0 - 2 + rr;
        gr = gr < 0 ? 0 : (gr > IMG_H - 1 ? IMG_H - 1 : gr);
        int ec = (wv == 0) ? (c0 - 4) : (c0 + 256);
        ec = (ec < 0 || ec > IMG_W - 4) ? c0 : ec;   // clamp; NEG-fixed below
        tile[rr * LROW + ((wv == 0) ? 0 : 65)] =
            *(const float4*)(ibase + (size_t)gr * IMG_W + ec);
    }
    __syncthreads();   // drains vmcnt(0)+lgkmcnt(0): all staging complete

    // ---- compute: wave wv outputs rows r0+wv*8 .. +7 from LDS ----
    const bool fixL = (strip == 0) && (lane == 0);
    const bool fixR = (strip == 7) && (lane == 63);
    const int lb = wv * 8;     // first LDS row this wave touches
    float4 H0, H1, H2, H3, H4, m0, m1, m2;
    unsigned bacc = 0, cnt = 0;
    const unsigned wIdx0 =
        (unsigned)(img * IMG_H + r0 + wv * 8 + (lane & 7)) * 64u +
        strip * 8u + (lane >> 3);

    COMPL(0, H0, m0);
    COMPL(1, H1, m1);
    COMPL(2, H2, m2);
    COMPL(3, H3, m0);
    COMPL(4, H4, m1);  OUT(m2, 0);
    COMPL(5, H0, m2);  OUT(m0, 1);
    COMPL(6, H1, m0);  OUT(m1, 2);
    COMPL(7, H2, m1);  OUT(m2, 3);
    COMPL(8, H3, m2);  OUT(m0, 4);
    COMPL(9, H4, m0);  OUT(m1, 5);
    COMPL(10, H0, m1); OUT(m2, 6);
    COMPL(11, H1, m2); OUT(m0, 7);
    MERGE();

    // ---- per-16-row-block counts (two waves per cb) ----
    unsigned s = cnt;
    s += __shfl_xor(s, 1);
    s += __shfl_xor(s, 2);
    s += __shfl_xor(s, 4);
    s += __shfl_xor(s, 8);
    s += __shfl_xor(s, 16);
    s += __shfl_xor(s, 32);
    if (lane == 0) wcnt[wv] = s;
    __syncthreads();
    if (t == 0) {
        const int cb0 = (img * IMG_H + r0) >> 4;
        bsum2[cb0 * 8 + strip] = wcnt[0] + wcnt[1];
        bsum2[(cb0 + 1) * 8 + strip] = wcnt[2] + wcnt[3];
    }
}

// ---------------------------------------------------------------------------
// K2: scan. Reduce 8 strip-sums per 16-row chunk (8192 slots -> 1024 cbs),
// exclusive scan, base[1024] = total. One 256-thread block.
// ---------------------------------------------------------------------------
__global__ __launch_bounds__(256) void nms_scan(const unsigned* __restrict__ bsum2,
                                                unsigned* __restrict__ base) {
    __shared__ unsigned wtot[4];
    const int t = threadIdx.x;
    const int lane = t & 63, wid = t >> 6;
    const uint4* p = (const uint4*)(bsum2 + t * 32);   // 4 cbs x 8 slots
    unsigned c[4];
#pragma unroll
    for (int i = 0; i < 4; ++i) {
        uint4 a = p[2 * i], bq = p[2 * i + 1];
        c[i] = a.x + a.y + a.z + a.w + bq.x + bq.y + bq.z + bq.w;
    }
    unsigned s0 = c[0], s1 = s0 + c[1], s2 = s1 + c[2], ts = s2 + c[3];
    unsigned sc = ts;
#pragma unroll
    for (int d = 1; d < 64; d <<= 1) {
        unsigned o = __shfl_up(sc, d);
        if (lane >= d) sc += o;
    }
    if (lane == 63) wtot[wid] = sc;
    __syncthreads();
    unsigned wpre = 0;
#pragma unroll
    for (int k = 0; k < 4; ++k) wpre += (k < wid) ? wtot[k] : 0u;
    unsigned excl = wpre + sc - ts;
    ((uint4*)base)[t] = make_uint4(excl, excl + s0, excl + s1, excl + s2);
    if (t == 255) base[1024] = wpre + sc;
}

// ---------------------------------------------------------------------------
// K3: ordered compaction (blocks 0..1023) + -1 tail fill (blocks 1024..),
// int4-vectorized tail body.
// ---------------------------------------------------------------------------
__global__ __launch_bounds__(256) void nms_compact(const unsigned* __restrict__ words,
                                                   const unsigned* __restrict__ base,
                                                   int* __restrict__ out) {
    const int t = threadIdx.x;
    const int b = blockIdx.x;
    if (b < 1024) {
        __shared__ unsigned wq[4];
        const int lane = t & 63, wid = t >> 6;
        uint4 q = ((const uint4*)(words + b * 1024))[t];
        unsigned wv[4] = {q.x, q.y, q.z, q.w};
        unsigned tsum = __popc(wv[0]) + __popc(wv[1]) + __popc(wv[2]) + __popc(wv[3]);
        unsigned sc = tsum;
#pragma unroll
        for (int d = 1; d < 64; d <<= 1) {
            unsigned o = __shfl_up(sc, d);
            if (lane >= d) sc += o;
        }
        if (lane == 63) wq[wid] = sc;
        __syncthreads();
        unsigned wpre = 0;
#pragma unroll
        for (int k = 0; k < 4; ++k) wpre += (k < wid) ? wq[k] : 0u;
        unsigned off = base[b] + wpre + sc - tsum;

        const unsigned gword0 = (unsigned)b * 1024u + (unsigned)t * 4u;
#pragma unroll
        for (int wi = 0; wi < 4; ++wi) {
            unsigned m = wv[wi];
            unsigned pbase = (gword0 + wi) << 5;
            while (m) {
                int bit = __builtin_ctz(m);
                m &= m - 1;
                unsigned ppix = pbase + (unsigned)bit;
                int hh = (int)((ppix >> 11) & 2047u);
                int ww = (int)(ppix & 2047u);
                if (off < (unsigned)MAX_PEAKS) {
                    out[off] = hh;
                    out[MAX_PEAKS + off] = ww;
                }
                ++off;
            }
        }
    } else {
        unsigned total = base[1024];
        if (total > (unsigned)MAX_PEAKS) total = MAX_PEAKS;
        unsigned tail = (unsigned)MAX_PEAKS - total;
        unsigned fb = (unsigned)(b - 1024);
        unsigned per = (tail + NFILL - 1) / NFILL;
        unsigned s = total + fb * per;
        unsigned e = s + per;
        if (s > (unsigned)MAX_PEAKS) s = MAX_PEAKS;
        if (e > (unsigned)MAX_PEAKS) e = MAX_PEAKS;
        unsigned a = (s + 3u) & ~3u;
        if (a > e) a = e;
        unsigned e4 = e & ~3u;
        if (e4 < a) e4 = a;
        if ((unsigned)t < a - s) {
            out[s + t] = -1;
            out[MAX_PEAKS + s + t] = -1;
        }
        const int4 m4 = make_int4(-1, -1, -1, -1);
        for (unsigned k = a / 4 + t; k < e4 / 4; k += 256) {
            ((int4*)out)[k] = m4;
            ((int4*)(out + MAX_PEAKS))[k] = m4;
        }
        if ((unsigned)t < e - e4) {
            out[e4 + t] = -1;
            out[MAX_PEAKS + e4 + t] = -1;
        }
    }
}

extern "C" void kernel_launch(void* const* d_in, const int* in_sizes, int n_in,
                              void* d_out, int out_size, void* d_ws, size_t ws_size,
                              hipStream_t stream) {
    const float* scores = (const float*)d_in[0];
    int* out = (int*)d_out;
    unsigned* words = (unsigned*)d_ws;            // 1,048,576 words (4 MB)
    unsigned* bsum2 = words + NWORDS;             // 8192 per-(16-row,strip) sums
    unsigned* base = bsum2 + 8192;                // 1025 (incl. total)

    nms_mask<<<4096, 256, 0, stream>>>(scores, words, bsum2);
    nms_scan<<<1, 256, 0, stream>>>(bsum2, base);
    nms_compact<<<1024 + NFILL, 256, 0, stream>>>(words, base, out);
}